// Round 17
// baseline (27.630 us; speedup 1.0000x reference)
//
#include <hip/hip_runtime.h>
#include <math.h>

// Problem constants: inputs (128, 64, 64, 32) fp32
#define BB 128
#define NN 64
#define DD 2048            // 64*32
#define NBLK 512           // 16 rows per block, 4 segments per batch
#define SEG 4

typedef float f4 __attribute__((ext_vector_type(4)));

__device__ __forceinline__ float wave_reduce_sum_down(float v) {
    #pragma unroll
    for (int off = 32; off > 0; off >>= 1)
        v += __shfl_down(v, off, 64);
    return v;
}

// 16B device-coherent write-through publish (no L2 allocate, no dirty lines,
// visible at coherence point after vmcnt(0)).
__device__ __forceinline__ void store_coherent(f4* p, f4 v) {
    asm volatile("global_store_dwordx4 %0, %1, off sc0 sc1 nt"
                 :: "v"(p), "v"(v) : "memory");
}

// Fused single worker kernel: R16-champion streaming core + in-kernel
// finisher chain. Publish = 16B sc0sc1 stores (R13's 8B atomic publish was
// the regression); consume = 16B sc0sc1 loads in one asm block with a
// trailing vmcnt(0). Rendezvous = relaxed agent atomics (R7/R8-proven).
__global__ __launch_bounds__(256) void fused_kernel(
        const float* __restrict__ x,
        float* __restrict__ vseg,        // [512][2048]
        double* __restrict__ diag_seg,   // [512]
        double* __restrict__ partials,   // [128]
        unsigned* __restrict__ bcnt,     // [128] pre-zeroed by memset node
        unsigned* __restrict__ gcnt,     // [1]   pre-zeroed
        float* __restrict__ out) {
    const int u = blockIdx.x;
    const int b = u >> 2, s = u & 3;
    const int t = threadIdx.x;
    const int lane = t & 63, w = t >> 6;     // 4 waves

    const float* xw = x + ((size_t)b * NN + s * 16 + w * 4) * DD;

    // ---- load all 4 rows up-front: 32 independent NT float4 per lane ----
    f4 a[4][8];
    #pragma unroll
    for (int r = 0; r < 4; ++r) {
        const f4* p = reinterpret_cast<const f4*>(xw + (size_t)r * DD);
        #pragma unroll
        for (int j = 0; j < 8; ++j)
            a[r][j] = __builtin_nontemporal_load(&p[lane + 64 * j]);
    }

    // ---- per-lane sumsq partials ----
    float ss[4];
    #pragma unroll
    for (int r = 0; r < 4; ++r) {
        float s4 = 0.f;
        #pragma unroll
        for (int j = 0; j < 8; ++j)
            s4 += a[r][j].x * a[r][j].x + a[r][j].y * a[r][j].y
                + a[r][j].z * a[r][j].z + a[r][j].w * a[r][j].w;
        ss[r] = s4;
    }

    // ---- packed butterfly ----
    #pragma unroll
    for (int off = 1; off < 64; off <<= 1) {
        float s0 = __shfl_xor(ss[0], off, 64);
        float s1 = __shfl_xor(ss[1], off, 64);
        float s2 = __shfl_xor(ss[2], off, 64);
        float s3 = __shfl_xor(ss[3], off, 64);
        ss[0] += s0; ss[1] += s1; ss[2] += s2; ss[3] += s3;
    }

    // ---- inv per row, diag, FMA into column accumulators ----
    f4 acc[8];
    #pragma unroll
    for (int j = 0; j < 8; ++j) acc[j] = (f4)(0.f);
    float diag = 0.f;                        // lane-uniform
    #pragma unroll
    for (int r = 0; r < 4; ++r) {
        const float inv = 1.0f / fmaxf(sqrtf(ss[r]), 1e-12f);
        diag += ss[r] * inv * inv;
        #pragma unroll
        for (int j = 0; j < 8; ++j) {
            acc[j].x = fmaf(a[r][j].x, inv, acc[j].x);
            acc[j].y = fmaf(a[r][j].y, inv, acc[j].y);
            acc[j].z = fmaf(a[r][j].z, inv, acc[j].z);
            acc[j].w = fmaf(a[r][j].w, inv, acc[j].w);
        }
    }

    // ---- cross-wave LDS combine ----
    __shared__ float lds[4][DD];
    __shared__ float dl[4];
    __shared__ float red[4];
    __shared__ int flag;
    f4* lw = reinterpret_cast<f4*>(lds[w]);
    #pragma unroll
    for (int j = 0; j < 8; ++j) lw[lane + 64 * j] = acc[j];
    if (lane == 0) dl[w] = diag;
    __syncthreads();

    f4 o0 = (f4)(0.f), o1 = (f4)(0.f);
    #pragma unroll
    for (int ww = 0; ww < 4; ++ww) {
        const f4* lr = reinterpret_cast<const f4*>(lds[ww]);
        o0 += lr[t];
        o1 += lr[t + 256];
    }
    // ---- publish segment vector: 16B coherent write-through ----
    f4* dst = reinterpret_cast<f4*>(vseg + (size_t)u * DD);
    store_coherent(&dst[t], o0);
    store_coherent(&dst[t + 256], o1);
    if (t == 0)
        __hip_atomic_store(&diag_seg[u],
                           (double)dl[0] + dl[1] + dl[2] + dl[3],
                           __ATOMIC_RELAXED, __HIP_MEMORY_SCOPE_AGENT);
    asm volatile("s_waitcnt vmcnt(0)" ::: "memory");   // drain publishes
    __syncthreads();

    if (t == 0) {
        unsigned old = __hip_atomic_fetch_add(&bcnt[b], 1u,
                        __ATOMIC_RELAXED, __HIP_MEMORY_SCOPE_AGENT);
        flag = (old == 3u) ? 1 : 0;
    }
    __syncthreads();
    if (!flag) return;

    // ---- batch finisher (4th arrival): coherent 16B reads of 4 segments ----
    {
        const f4* s0p = reinterpret_cast<const f4*>(vseg + (size_t)(b * SEG + 0) * DD);
        const f4* s1p = reinterpret_cast<const f4*>(vseg + (size_t)(b * SEG + 1) * DD);
        const f4* s2p = reinterpret_cast<const f4*>(vseg + (size_t)(b * SEG + 2) * DD);
        const f4* s3p = reinterpret_cast<const f4*>(vseg + (size_t)(b * SEG + 3) * DD);
        f4 r0, r1, r2, r3, r4, r5, r6, r7;
        asm volatile(
            "global_load_dwordx4 %0, %8, off sc0 sc1\n\t"
            "global_load_dwordx4 %1, %9, off sc0 sc1\n\t"
            "global_load_dwordx4 %2, %10, off sc0 sc1\n\t"
            "global_load_dwordx4 %3, %11, off sc0 sc1\n\t"
            "global_load_dwordx4 %4, %12, off sc0 sc1\n\t"
            "global_load_dwordx4 %5, %13, off sc0 sc1\n\t"
            "global_load_dwordx4 %6, %14, off sc0 sc1\n\t"
            "global_load_dwordx4 %7, %15, off sc0 sc1\n\t"
            "s_waitcnt vmcnt(0)"
            : "=&v"(r0), "=&v"(r1), "=&v"(r2), "=&v"(r3),
              "=&v"(r4), "=&v"(r5), "=&v"(r6), "=&v"(r7)
            : "v"(&s0p[t]), "v"(&s1p[t]), "v"(&s2p[t]), "v"(&s3p[t]),
              "v"(&s0p[t + 256]), "v"(&s1p[t + 256]),
              "v"(&s2p[t + 256]), "v"(&s3p[t + 256])
            : "memory");
        f4 c0 = r0 + r1 + r2 + r3;
        f4 c1 = r4 + r5 + r6 + r7;
        float p = c0.x * c0.x + c0.y * c0.y + c0.z * c0.z + c0.w * c0.w
                + c1.x * c1.x + c1.y * c1.y + c1.z * c1.z + c1.w * c1.w;
        p = wave_reduce_sum_down(p);
        if (lane == 0) red[w] = p;
    }
    __syncthreads();
    if (t == 0) {
        double sp = (double)red[0] + (double)red[1]
                  + (double)red[2] + (double)red[3];
        double dp = 0.0;
        #pragma unroll
        for (int o = 0; o < SEG; ++o)
            dp += __hip_atomic_load(&diag_seg[b * SEG + o],
                        __ATOMIC_RELAXED, __HIP_MEMORY_SCOPE_AGENT);
        __hip_atomic_store(&partials[b], sp - dp,
                           __ATOMIC_RELAXED, __HIP_MEMORY_SCOPE_AGENT);
        asm volatile("s_waitcnt vmcnt(0)" ::: "memory");   // drain my store
        unsigned old = __hip_atomic_fetch_add(gcnt, 1u,
                        __ATOMIC_RELAXED, __HIP_MEMORY_SCOPE_AGENT);
        flag = (old == (unsigned)(BB - 1)) ? 1 : 0;
    }
    __syncthreads();
    if (!flag) return;

    // ---- global finisher: fixed-order tree over 128 batch partials ----
    __shared__ double sd[BB];
    if (t < BB)
        sd[t] = __hip_atomic_load(&partials[t],
                        __ATOMIC_RELAXED, __HIP_MEMORY_SCOPE_AGENT);
    __syncthreads();
    #pragma unroll
    for (int off = BB / 2; off > 0; off >>= 1) {
        if (t < off) sd[t] += sd[t + off];
        __syncthreads();
    }
    if (t == 0) out[0] = (float)(sd[0] / (double)BB);
}

extern "C" void kernel_launch(void* const* d_in, const int* in_sizes, int n_in,
                              void* d_out, int out_size, void* d_ws, size_t ws_size,
                              hipStream_t stream) {
    const float* x = (const float*)d_in[0];
    float* out = (float*)d_out;
    char* ws = (char*)d_ws;

    const size_t vbytes = (size_t)NBLK * DD * 4;           // 4 MB
    float* vseg       = (float*)ws;
    double* diag_seg  = (double*)(ws + vbytes);            // 4 KB
    double* partials  = (double*)(ws + vbytes + 4096);     // 1 KB
    unsigned* bcnt    = (unsigned*)(ws + vbytes + 4096 + 1024);  // 512 B
    unsigned* gcnt    = (unsigned*)(ws + vbytes + 4096 + 1024 + 512);

    hipMemsetAsync(bcnt, 0, 516, stream);                  // counters only
    fused_kernel<<<NBLK, 256, 0, stream>>>(x, vseg, diag_seg, partials,
                                           bcnt, gcnt, out);
}

// Round 18
// 22.689 us; speedup vs baseline: 1.2178x; 1.2178x over previous
//
#include <hip/hip_runtime.h>
#include <math.h>

// Problem constants: inputs (128, 64, 64, 32) fp32
#define BB 128
#define NN 64
#define DD 2048            // 64*32
#define NBLK1 1024         // 8 rows per block, 8 segments per batch
#define SEG 8

typedef float f4 __attribute__((ext_vector_type(4)));

__device__ __forceinline__ float wave_reduce_sum_down(float v) {
    #pragma unroll
    for (int off = 32; off > 0; off >>= 1)
        v += __shfl_down(v, off, 64);
    return v;
}

// K1: 1024 blocks x 256 thr; wave owns 2 rows (a[2][8] = 64 VGPR data ->
// ~115 VGPR total -> 16 waves/CU = 4 waves/SIMD, double the RPW=4 champion's
// latency hiding). NT loads (single-touch, no L2 alloc), packed butterfly,
// NT stores for vseg (no dirty-L2 drain at kernel end). Block 0 zeroes the
// K2 counter (kernel boundary = visibility fence).
__global__ __launch_bounds__(256, 4) void stream_kernel(
        const float* __restrict__ x,
        float* __restrict__ vseg,        // [1024][2048]
        float* __restrict__ diag_seg,    // [1024]
        unsigned* __restrict__ counter) {
    const int u = blockIdx.x;
    const int b = u >> 3, s = u & 7;     // batch, 8-row segment
    const int t = threadIdx.x;
    const int lane = t & 63, w = t >> 6; // 4 waves

    if (u == 0 && t == 0) *counter = 0;  // visible to K2 at kernel boundary

    const float* xw = x + ((size_t)b * NN + s * 8 + w * 2) * DD;

    // ---- load both rows up-front: 16 independent NT float4 per lane ----
    f4 a[2][8];
    #pragma unroll
    for (int r = 0; r < 2; ++r) {
        const f4* p = reinterpret_cast<const f4*>(xw + (size_t)r * DD);
        #pragma unroll
        for (int j = 0; j < 8; ++j)
            a[r][j] = __builtin_nontemporal_load(&p[lane + 64 * j]);
    }

    // ---- per-lane sumsq partials ----
    float ss[2];
    #pragma unroll
    for (int r = 0; r < 2; ++r) {
        float s4 = 0.f;
        #pragma unroll
        for (int j = 0; j < 8; ++j)
            s4 += a[r][j].x * a[r][j].x + a[r][j].y * a[r][j].y
                + a[r][j].z * a[r][j].z + a[r][j].w * a[r][j].w;
        ss[r] = s4;
    }

    // ---- packed butterfly: 6 steps x 2 independent shfls ----
    #pragma unroll
    for (int off = 1; off < 64; off <<= 1) {
        float s0 = __shfl_xor(ss[0], off, 64);
        float s1 = __shfl_xor(ss[1], off, 64);
        ss[0] += s0; ss[1] += s1;
    }

    // ---- inv per row, diag, FMA rows into column accumulators ----
    f4 acc[8];
    #pragma unroll
    for (int j = 0; j < 8; ++j) acc[j] = (f4)(0.f);
    float diag = 0.f;                    // lane-uniform
    #pragma unroll
    for (int r = 0; r < 2; ++r) {
        const float inv = 1.0f / fmaxf(sqrtf(ss[r]), 1e-12f);
        diag += ss[r] * inv * inv;       // ||att_row||^2
        #pragma unroll
        for (int j = 0; j < 8; ++j) {
            acc[j].x = fmaf(a[r][j].x, inv, acc[j].x);
            acc[j].y = fmaf(a[r][j].y, inv, acc[j].y);
            acc[j].z = fmaf(a[r][j].z, inv, acc[j].z);
            acc[j].w = fmaf(a[r][j].w, inv, acc[j].w);
        }
    }

    // ---- cross-wave combine: [4][2048] floats = 32 KB LDS ----
    __shared__ float lds[4][DD];
    __shared__ float dl[4];
    f4* lw = reinterpret_cast<f4*>(lds[w]);
    #pragma unroll
    for (int j = 0; j < 8; ++j) lw[lane + 64 * j] = acc[j];
    if (lane == 0) dl[w] = diag;
    __syncthreads();

    // thread t -> float4 indices t, t+256 (16B stride: conflict-free)
    f4 o0 = (f4)(0.f), o1 = (f4)(0.f);
    #pragma unroll
    for (int ww = 0; ww < 4; ++ww) {
        const f4* lr = reinterpret_cast<const f4*>(lds[ww]);
        o0 += lr[t];
        o1 += lr[t + 256];
    }
    f4* dst = reinterpret_cast<f4*>(vseg + (size_t)u * DD);
    __builtin_nontemporal_store(o0, &dst[t]);        // no dirty L2 lines
    __builtin_nontemporal_store(o1, &dst[t + 256]);
    if (t == 0)
        __builtin_nontemporal_store(dl[0] + dl[1] + dl[2] + dl[3],
                                    &diag_seg[u]);
}

// K2: per-batch combine of 8 segment vectors + fence-free last-block tree.
__global__ __launch_bounds__(256) void combine_kernel(
        const float* __restrict__ vseg,
        const float* __restrict__ diag_seg,
        double* __restrict__ partials,   // [128]
        unsigned* __restrict__ counter,  // zeroed by K1
        float* __restrict__ out) {
    const int b = blockIdx.x;
    const int t = threadIdx.x;
    const int lane = t & 63, wid = t >> 6;   // 4 waves

    __shared__ float red[4];
    __shared__ int flag;
    __shared__ double sd[BB];

    f4 c0 = (f4)(0.f), c1 = (f4)(0.f);
    #pragma unroll
    for (int o = 0; o < SEG; ++o) {
        const f4* src = reinterpret_cast<const f4*>(
            vseg + (size_t)(b * SEG + o) * DD);
        c0 += __builtin_nontemporal_load(&src[t]);       // single-touch
        c1 += __builtin_nontemporal_load(&src[t + 256]);
    }
    float p = c0.x * c0.x + c0.y * c0.y + c0.z * c0.z + c0.w * c0.w
            + c1.x * c1.x + c1.y * c1.y + c1.z * c1.z + c1.w * c1.w;
    p = wave_reduce_sum_down(p);
    if (lane == 0) red[wid] = p;
    __syncthreads();

    if (t == 0) {
        double sp = (double)red[0] + (double)red[1]
                  + (double)red[2] + (double)red[3];
        double dp = 0.0;
        #pragma unroll
        for (int o = 0; o < SEG; ++o) dp += (double)diag_seg[b * SEG + o];
        __hip_atomic_store(&partials[b], sp - dp,
                           __ATOMIC_RELAXED, __HIP_MEMORY_SCOPE_AGENT);
        asm volatile("s_waitcnt vmcnt(0)" ::: "memory");   // drain my store
        unsigned old = __hip_atomic_fetch_add(counter, 1u,
                        __ATOMIC_RELAXED, __HIP_MEMORY_SCOPE_AGENT);
        flag = (old == (unsigned)(BB - 1)) ? 1 : 0;
    }
    __syncthreads();
    if (!flag) return;

    if (t < BB)
        sd[t] = __hip_atomic_load(&partials[t],
                        __ATOMIC_RELAXED, __HIP_MEMORY_SCOPE_AGENT);
    __syncthreads();
    #pragma unroll
    for (int off = BB / 2; off > 0; off >>= 1) {
        if (t < off) sd[t] += sd[t + off];
        __syncthreads();
    }
    if (t == 0) out[0] = (float)(sd[0] / (double)BB);
}

extern "C" void kernel_launch(void* const* d_in, const int* in_sizes, int n_in,
                              void* d_out, int out_size, void* d_ws, size_t ws_size,
                              hipStream_t stream) {
    const float* x = (const float*)d_in[0];
    float* out = (float*)d_out;
    char* ws = (char*)d_ws;

    const size_t vbytes = (size_t)NBLK1 * DD * 4;          // 8 MB
    float* vseg       = (float*)ws;
    float* diag_seg   = (float*)(ws + vbytes);             // 4 KB
    double* partials  = (double*)(ws + vbytes + 4096);     // 1 KB
    unsigned* counter = (unsigned*)(ws + vbytes + 4096 + 1024);

    stream_kernel<<<NBLK1, 256, 0, stream>>>(x, vseg, diag_seg, counter);
    combine_kernel<<<BB, 256, 0, stream>>>(vseg, diag_seg, partials,
                                           counter, out);
}